// Round 1
// baseline (206.705 us; speedup 1.0000x reference)
//
#include <hip/hip_runtime.h>

// DiceLoss: B=2, C=14, D=48, H=256, W=256, organs 1..13, weights all 1.0.
// Collapses to per-batch sums: S = sum of pred at target channel (t in 1..13),
// Q = sum of pred^2 over channels 1..13, cnt = #voxels with t>=1.
// dice_stage = 2S/(Q + cnt + 13*EPS); out = mean_b(2 - dice1 - dice2).

namespace {
constexpr int BATCH = 2;
constexpr int CH = 14;
constexpr int ORGANS = 13;
constexpr long long DHW = 48LL * 256 * 256;   // 3145728 voxels per (b, channel)
constexpr long long NV4 = DHW / 4;            // 786432 float4 groups per batch
constexpr double EPS = 1e-05;
}

__global__ __launch_bounds__(256) void dice_partial(
    const float* __restrict__ p1g, const float* __restrict__ p2g,
    const int* __restrict__ tg, double* __restrict__ acc)
{
    const int b = blockIdx.y;
    // Base points at channel 1 (channel 0 of pred is never used).
    const float4* __restrict__ p1 =
        reinterpret_cast<const float4*>(p1g + ((long long)b * CH + 1) * DHW);
    const float4* __restrict__ p2 =
        reinterpret_cast<const float4*>(p2g + ((long long)b * CH + 1) * DHW);
    const int4* __restrict__ tt =
        reinterpret_cast<const int4*>(tg + (long long)b * DHW);

    float s1 = 0.f, q1 = 0.f, s2 = 0.f, q2 = 0.f, cn = 0.f;
    const long long stride = (long long)gridDim.x * blockDim.x;
    for (long long i = (long long)blockIdx.x * blockDim.x + threadIdx.x;
         i < NV4; i += stride) {
        const int4 t = tt[i];
        cn += (float)((t.x > 0) + (t.y > 0) + (t.z > 0) + (t.w > 0));
        #pragma unroll
        for (int c = 0; c < ORGANS; ++c) {
            const long long off = i + (long long)c * (DHW / 4);
            const float4 a = p1[off];
            const float4 v = p2[off];
            q1 = fmaf(a.x, a.x, q1); q1 = fmaf(a.y, a.y, q1);
            q1 = fmaf(a.z, a.z, q1); q1 = fmaf(a.w, a.w, q1);
            q2 = fmaf(v.x, v.x, q2); q2 = fmaf(v.y, v.y, q2);
            q2 = fmaf(v.z, v.z, q2); q2 = fmaf(v.w, v.w, q2);
            const int cc = c + 1;
            s1 += (t.x == cc ? a.x : 0.f) + (t.y == cc ? a.y : 0.f)
                + (t.z == cc ? a.z : 0.f) + (t.w == cc ? a.w : 0.f);
            s2 += (t.x == cc ? v.x : 0.f) + (t.y == cc ? v.y : 0.f)
                + (t.z == cc ? v.z : 0.f) + (t.w == cc ? v.w : 0.f);
        }
    }

    // Block reduction: wave shuffle (64 lanes) then LDS across 4 waves.
    float vals[5] = {s1, q1, s2, q2, cn};
    #pragma unroll
    for (int k = 0; k < 5; ++k) {
        float v = vals[k];
        #pragma unroll
        for (int off = 32; off > 0; off >>= 1) v += __shfl_down(v, off, 64);
        vals[k] = v;
    }
    __shared__ float red[4][5];
    const int lane = threadIdx.x & 63;
    const int wid = threadIdx.x >> 6;
    if (lane == 0) {
        #pragma unroll
        for (int k = 0; k < 5; ++k) red[wid][k] = vals[k];
    }
    __syncthreads();
    if (threadIdx.x == 0) {
        #pragma unroll
        for (int k = 0; k < 5; ++k) {
            const float v = red[0][k] + red[1][k] + red[2][k] + red[3][k];
            atomicAdd(&acc[b * 5 + k], (double)v);
        }
    }
}

__global__ void dice_final(const double* __restrict__ acc, float* __restrict__ out)
{
    if (threadIdx.x == 0 && blockIdx.x == 0) {
        double total = 0.0;
        for (int b = 0; b < BATCH; ++b) {
            const double s1 = acc[b * 5 + 0], q1 = acc[b * 5 + 1];
            const double s2 = acc[b * 5 + 2], q2 = acc[b * 5 + 3];
            const double cn = acc[b * 5 + 4];
            const double den1 = q1 + cn + (double)ORGANS * EPS;
            const double den2 = q2 + cn + (double)ORGANS * EPS;
            total += 2.0 - (2.0 * s1 / den1 + 2.0 * s2 / den2);
        }
        *out = (float)(total / BATCH);
    }
}

extern "C" void kernel_launch(void* const* d_in, const int* in_sizes, int n_in,
                              void* d_out, int out_size, void* d_ws, size_t ws_size,
                              hipStream_t stream)
{
    const float* p1 = (const float*)d_in[0];
    const float* p2 = (const float*)d_in[1];
    const int* tg = (const int*)d_in[2];
    float* out = (float*)d_out;
    double* acc = (double*)d_ws;

    // d_ws is poisoned once (0xAA) and never restored between replays: zero it
    // every launch (async memset is graph-capture safe).
    hipMemsetAsync(d_ws, 0, BATCH * 5 * sizeof(double), stream);

    dim3 block(256);
    dim3 grid(1024, BATCH);   // 2048 blocks = 8/CU; 3 float4 groups per thread
    dice_partial<<<grid, block, 0, stream>>>(p1, p2, tg, acc);
    dice_final<<<1, 64, 0, stream>>>(acc, out);
}

// Round 2
// 196.880 us; speedup vs baseline: 1.0499x; 1.0499x over previous
//
#include <hip/hip_runtime.h>

// DiceLoss: B=2, C=14, D=48, H=256, W=256, organs 1..13, weights all 1.0.
// Per batch b: S = sum of pred at target channel (t in 1..13),
//              Q = sum over c=1..13 of pred[c]^2, cnt = #{t>=1}.
// dice_stage = 2S/(Q + cnt + 13*EPS); out = mean_b(2 - dice1 - dice2).
//
// R2 structure: one block owns one (b, channel) slice and streams it
// CONTIGUOUSLY (3 sequential streams per wave: target, p1, p2) instead of 27
// channel-strided streams per wave (R1: latency-bound at 2.8 TB/s consumed).
// cnt is recovered as sum over slices of #(t == c+1).

namespace {
constexpr int BATCH = 2;
constexpr int CH = 14;
constexpr int ORGANS = 13;
constexpr long long DHW = 48LL * 256 * 256;   // 3145728 voxels per (b, channel)
constexpr long long NV4 = DHW / 4;            // 786432 vec4 groups per slice
constexpr int BLOCKS_PER_SLICE = 64;          // 64*256*48 == NV4 exactly, no tail
constexpr double EPS = 1e-05;
}

__global__ __launch_bounds__(256) void dice_slices(
    const float* __restrict__ p1g, const float* __restrict__ p2g,
    const int* __restrict__ tg, double* __restrict__ acc)
{
    const int c = blockIdx.y;          // 0..12 -> channel c+1
    const int b = blockIdx.z;          // 0..1
    const int cc = c + 1;

    const float4* __restrict__ p1 =
        reinterpret_cast<const float4*>(p1g + ((long long)b * CH + cc) * DHW);
    const float4* __restrict__ p2 =
        reinterpret_cast<const float4*>(p2g + ((long long)b * CH + cc) * DHW);
    const int4* __restrict__ tt =
        reinterpret_cast<const int4*>(tg + (long long)b * DHW);

    float s1 = 0.f, q1 = 0.f, s2 = 0.f, q2 = 0.f, cn = 0.f;
    const long long stride = (long long)BLOCKS_PER_SLICE * 256;
    long long i = (long long)blockIdx.x * 256 + threadIdx.x;
    #pragma unroll 4
    for (int it = 0; it < (int)(NV4 / stride); ++it, i += stride) {
        const int4 t = tt[i];
        const float4 a = p1[i];
        const float4 v = p2[i];
        q1 = fmaf(a.x, a.x, q1); q1 = fmaf(a.y, a.y, q1);
        q1 = fmaf(a.z, a.z, q1); q1 = fmaf(a.w, a.w, q1);
        q2 = fmaf(v.x, v.x, q2); q2 = fmaf(v.y, v.y, q2);
        q2 = fmaf(v.z, v.z, q2); q2 = fmaf(v.w, v.w, q2);
        cn += (float)((t.x == cc) + (t.y == cc) + (t.z == cc) + (t.w == cc));
        s1 += (t.x == cc ? a.x : 0.f) + (t.y == cc ? a.y : 0.f)
            + (t.z == cc ? a.z : 0.f) + (t.w == cc ? a.w : 0.f);
        s2 += (t.x == cc ? v.x : 0.f) + (t.y == cc ? v.y : 0.f)
            + (t.z == cc ? v.z : 0.f) + (t.w == cc ? v.w : 0.f);
    }

    // Block reduction: wave shuffle (64 lanes) then LDS across 4 waves.
    float vals[5] = {s1, q1, s2, q2, cn};
    #pragma unroll
    for (int k = 0; k < 5; ++k) {
        float v = vals[k];
        #pragma unroll
        for (int off = 32; off > 0; off >>= 1) v += __shfl_down(v, off, 64);
        vals[k] = v;
    }
    __shared__ float red[4][5];
    const int lane = threadIdx.x & 63;
    const int wid = threadIdx.x >> 6;
    if (lane == 0) {
        #pragma unroll
        for (int k = 0; k < 5; ++k) red[wid][k] = vals[k];
    }
    __syncthreads();
    if (threadIdx.x == 0) {
        #pragma unroll
        for (int k = 0; k < 5; ++k) {
            const float v = red[0][k] + red[1][k] + red[2][k] + red[3][k];
            atomicAdd(&acc[b * 5 + k], (double)v);
        }
    }
}

__global__ void dice_final(const double* __restrict__ acc, float* __restrict__ out)
{
    if (threadIdx.x == 0 && blockIdx.x == 0) {
        double total = 0.0;
        for (int b = 0; b < BATCH; ++b) {
            const double s1 = acc[b * 5 + 0], q1 = acc[b * 5 + 1];
            const double s2 = acc[b * 5 + 2], q2 = acc[b * 5 + 3];
            const double cn = acc[b * 5 + 4];
            const double den1 = q1 + cn + (double)ORGANS * EPS;
            const double den2 = q2 + cn + (double)ORGANS * EPS;
            total += 2.0 - (2.0 * s1 / den1 + 2.0 * s2 / den2);
        }
        *out = (float)(total / BATCH);
    }
}

extern "C" void kernel_launch(void* const* d_in, const int* in_sizes, int n_in,
                              void* d_out, int out_size, void* d_ws, size_t ws_size,
                              hipStream_t stream)
{
    const float* p1 = (const float*)d_in[0];
    const float* p2 = (const float*)d_in[1];
    const int* tg = (const int*)d_in[2];
    float* out = (float*)d_out;
    double* acc = (double*)d_ws;

    // d_ws is poisoned (0xAA) once and never re-poisoned between replays:
    // zero it every launch (async memset is graph-capture safe).
    hipMemsetAsync(d_ws, 0, BATCH * 5 * sizeof(double), stream);

    dim3 block(256);
    dim3 grid(BLOCKS_PER_SLICE, ORGANS, BATCH);   // 64 x 13 x 2 = 1664 blocks
    dice_slices<<<grid, block, 0, stream>>>(p1, p2, tg, acc);
    dice_final<<<1, 64, 0, stream>>>(acc, out);
}

// Round 3
// 159.858 us; speedup vs baseline: 1.2931x; 1.2316x over previous
//
#include <hip/hip_runtime.h>

// DiceLoss: B=2, C=14, D=48, H=256, W=256, organs 1..13, weights all 1.0.
// Per batch b: S = sum of pred at target channel (t in 1..13),
//              Q = sum over c=1..13 of pred[c]^2, cnt = #{t>=1}.
// dice_stage = 2S/(Q + cnt + 13*EPS); out = mean_b(2 - dice1 - dice2).
//
// R3: R1/R2 were per-wave-MLP-bound (VGPR=20 -> ~1 outstanding load/wave,
// both landed ~240us regardless of access pattern). This version batches all
// 27 loads per iteration (t + 13 a + 13 v) into unrolled register arrays
// BEFORE any use -> ~27KB in flight per wave. Target is read once (minimal
// logical traffic ~680 MB).

namespace {
constexpr int BATCH = 2;
constexpr int CH = 14;
constexpr int ORGANS = 13;
constexpr long long DHW = 48LL * 256 * 256;   // 3145728 voxels per (b, channel)
constexpr long long NV4 = DHW / 4;            // 786432 vec4 groups per channel
constexpr int GRID_X = 512;                   // 512*256 threads: NV4/131072 = 6 iters exact
constexpr int ITERS = (int)(NV4 / (GRID_X * 256));
constexpr double EPS = 1e-05;
}

__global__ __launch_bounds__(256) void dice_batched(
    const float* __restrict__ p1g, const float* __restrict__ p2g,
    const int* __restrict__ tg, double* __restrict__ acc)
{
    const int b = blockIdx.y;
    // Channel 0 of pred is never used; base at channel 1.
    const float4* __restrict__ p1 =
        reinterpret_cast<const float4*>(p1g + ((long long)b * CH + 1) * DHW);
    const float4* __restrict__ p2 =
        reinterpret_cast<const float4*>(p2g + ((long long)b * CH + 1) * DHW);
    const int4* __restrict__ tt =
        reinterpret_cast<const int4*>(tg + (long long)b * DHW);

    float s1 = 0.f, q1 = 0.f, s2 = 0.f, q2 = 0.f, cn = 0.f;
    long long i = (long long)blockIdx.x * 256 + threadIdx.x;
    const long long stride = (long long)GRID_X * 256;

    for (int it = 0; it < ITERS; ++it, i += stride) {
        // Issue ALL loads first (27 in flight), consume after.
        const int4 t = tt[i];
        float4 a[ORGANS], v[ORGANS];
        #pragma unroll
        for (int c = 0; c < ORGANS; ++c) a[c] = p1[i + (long long)c * NV4];
        #pragma unroll
        for (int c = 0; c < ORGANS; ++c) v[c] = p2[i + (long long)c * NV4];

        cn += (float)((t.x > 0) + (t.y > 0) + (t.z > 0) + (t.w > 0));
        #pragma unroll
        for (int c = 0; c < ORGANS; ++c) {
            const int cc = c + 1;
            const float4 A = a[c], V = v[c];
            q1 = fmaf(A.x, A.x, q1); q1 = fmaf(A.y, A.y, q1);
            q1 = fmaf(A.z, A.z, q1); q1 = fmaf(A.w, A.w, q1);
            q2 = fmaf(V.x, V.x, q2); q2 = fmaf(V.y, V.y, q2);
            q2 = fmaf(V.z, V.z, q2); q2 = fmaf(V.w, V.w, q2);
            s1 += (t.x == cc ? A.x : 0.f) + (t.y == cc ? A.y : 0.f)
                + (t.z == cc ? A.z : 0.f) + (t.w == cc ? A.w : 0.f);
            s2 += (t.x == cc ? V.x : 0.f) + (t.y == cc ? V.y : 0.f)
                + (t.z == cc ? V.z : 0.f) + (t.w == cc ? V.w : 0.f);
        }
    }

    // Block reduction: wave shuffle (64 lanes) then LDS across 4 waves.
    float vals[5] = {s1, q1, s2, q2, cn};
    #pragma unroll
    for (int k = 0; k < 5; ++k) {
        float v = vals[k];
        #pragma unroll
        for (int off = 32; off > 0; off >>= 1) v += __shfl_down(v, off, 64);
        vals[k] = v;
    }
    __shared__ float red[4][5];
    const int lane = threadIdx.x & 63;
    const int wid = threadIdx.x >> 6;
    if (lane == 0) {
        #pragma unroll
        for (int k = 0; k < 5; ++k) red[wid][k] = vals[k];
    }
    __syncthreads();
    if (threadIdx.x == 0) {
        #pragma unroll
        for (int k = 0; k < 5; ++k) {
            const float v = red[0][k] + red[1][k] + red[2][k] + red[3][k];
            atomicAdd(&acc[b * 5 + k], (double)v);
        }
    }
}

__global__ void dice_final(const double* __restrict__ acc, float* __restrict__ out)
{
    if (threadIdx.x == 0 && blockIdx.x == 0) {
        double total = 0.0;
        for (int b = 0; b < BATCH; ++b) {
            const double s1 = acc[b * 5 + 0], q1 = acc[b * 5 + 1];
            const double s2 = acc[b * 5 + 2], q2 = acc[b * 5 + 3];
            const double cn = acc[b * 5 + 4];
            const double den1 = q1 + cn + (double)ORGANS * EPS;
            const double den2 = q2 + cn + (double)ORGANS * EPS;
            total += 2.0 - (2.0 * s1 / den1 + 2.0 * s2 / den2);
        }
        *out = (float)(total / BATCH);
    }
}

extern "C" void kernel_launch(void* const* d_in, const int* in_sizes, int n_in,
                              void* d_out, int out_size, void* d_ws, size_t ws_size,
                              hipStream_t stream)
{
    const float* p1 = (const float*)d_in[0];
    const float* p2 = (const float*)d_in[1];
    const int* tg = (const int*)d_in[2];
    float* out = (float*)d_out;
    double* acc = (double*)d_ws;

    // d_ws is poisoned (0xAA) once and never re-poisoned between replays:
    // zero it every launch (async memset is graph-capture safe).
    hipMemsetAsync(d_ws, 0, BATCH * 5 * sizeof(double), stream);

    dim3 block(256);
    dim3 grid(GRID_X, BATCH);   // 1024 blocks total -> 4/CU, fully co-resident
    dice_batched<<<grid, block, 0, stream>>>(p1, p2, tg, acc);
    dice_final<<<1, 64, 0, stream>>>(acc, out);
}

// Round 4
// 156.908 us; speedup vs baseline: 1.3174x; 1.0188x over previous
//
#include <hip/hip_runtime.h>

// DiceLoss: B=2, C=14, D=48, H=256, W=256, organs 1..13, weights all 1.0.
// Per batch b: S = sum of pred at target channel (t in 1..13),
//              Q = sum over c=1..13 of pred[c]^2, cnt = #{t>=1}.
// dice_stage = 2S/(Q + cnt + 13*EPS); out = mean_b(2 - dice1 - dice2).
//
// R4: contiguous streaming (R2) + deep load batching (R3), perfect balance.
// Flat group index g over (b, c in 1..13, i): used pred channels are
// CONTIGUOUS per batch, so pred addr = g + (1+b)*NV4 - pure sequential
// streams per block. 1024 blocks x 256 thr x 78 groups covers the space
// exactly. cnt recovered as sum over c of #(t==c+1). Per-block partials
// written directly (no memset, no atomics).

namespace {
constexpr int BATCH = 2;
constexpr int CH = 14;
constexpr int ORGANS = 13;
constexpr unsigned NV4 = 786432u;            // DHW/4 groups per channel slice
constexpr unsigned RSPAN = 13u * NV4;        // 10223616 groups per batch
constexpr int NBLK = 1024;                   // 512 chunks per batch exactly
constexpr int TPB = 256;
constexpr int UNROLL = 6;
constexpr int OUTER = 13;                    // 78 groups per thread = 13*6
constexpr unsigned CHUNK = 78u * TPB;        // 19968 groups per block
constexpr double EPS = 1e-05;
}

__global__ __launch_bounds__(TPB, 4) void dice_stream(
    const float* __restrict__ p1g, const float* __restrict__ p2g,
    const int* __restrict__ tg, double* __restrict__ part)
{
    const unsigned blk = blockIdx.x;
    const unsigned b = blk >> 9;             // batch; chunks never straddle batches
    const float4* __restrict__ pA =
        reinterpret_cast<const float4*>(p1g) + (unsigned)((b * CH + 1) * NV4 - (1u + b) * NV4);
    const float4* __restrict__ pB =
        reinterpret_cast<const float4*>(p2g) + (unsigned)((b * CH + 1) * NV4 - (1u + b) * NV4);
    // pA/pB are pre-shifted so pA[g] = pred1[(b*14+1)*NV4 + (g - b*RSPAN)]:
    //   (b*14+1)*NV4 + g - b*13*NV4 = g + (1+b)*NV4  ->  shift = (1+b)*NV4 applied via index below.
    const int4* __restrict__ pT = reinterpret_cast<const int4*>(tg) + b * NV4;

    const unsigned shift = (1u + b) * NV4;   // pred index = g + shift (g is global flat group)
    unsigned g = blk * CHUNK + threadIdx.x;  // global flat group index
    unsigned r = g - b * RSPAN;              // group index within this batch [0, RSPAN)

    float s1 = 0.f, q1 = 0.f, s2 = 0.f, q2 = 0.f, cn = 0.f;
    const float4* __restrict__ pA0 = reinterpret_cast<const float4*>(p1g) + b * CH * NV4 + NV4;
    const float4* __restrict__ pB0 = reinterpret_cast<const float4*>(p2g) + b * CH * NV4 + NV4;

    for (int it = 0; it < OUTER; ++it, r += UNROLL * TPB) {
        int4 t[UNROLL]; float4 a[UNROLL], v[UNROLL]; int cc[UNROLL];
        #pragma unroll
        for (int u = 0; u < UNROLL; ++u) {
            const unsigned ru = r + u * TPB;
            const unsigned c = ru / NV4;         // 0..12, wave-uniform (NV4 % 256 == 0)
            const unsigned iu = ru - c * NV4;
            cc[u] = (int)c + 1;
            t[u] = pT[iu];
            a[u] = pA0[ru];
            v[u] = pB0[ru];
        }
        #pragma unroll
        for (int u = 0; u < UNROLL; ++u) {
            const int4 t4 = t[u]; const float4 A = a[u], V = v[u]; const int m = cc[u];
            q1 = fmaf(A.x, A.x, q1); q1 = fmaf(A.y, A.y, q1);
            q1 = fmaf(A.z, A.z, q1); q1 = fmaf(A.w, A.w, q1);
            q2 = fmaf(V.x, V.x, q2); q2 = fmaf(V.y, V.y, q2);
            q2 = fmaf(V.z, V.z, q2); q2 = fmaf(V.w, V.w, q2);
            const bool ex = (t4.x == m), ey = (t4.y == m),
                       ez = (t4.z == m), ew = (t4.w == m);
            cn += (float)((int)ex + (int)ey + (int)ez + (int)ew);
            s1 += (ex ? A.x : 0.f) + (ey ? A.y : 0.f)
                + (ez ? A.z : 0.f) + (ew ? A.w : 0.f);
            s2 += (ex ? V.x : 0.f) + (ey ? V.y : 0.f)
                + (ez ? V.z : 0.f) + (ew ? V.w : 0.f);
        }
    }

    // Block reduction: wave shuffle (64 lanes) then LDS across 4 waves.
    float vals[5] = {s1, q1, s2, q2, cn};
    #pragma unroll
    for (int k = 0; k < 5; ++k) {
        float v = vals[k];
        #pragma unroll
        for (int off = 32; off > 0; off >>= 1) v += __shfl_down(v, off, 64);
        vals[k] = v;
    }
    __shared__ float red[4][5];
    const int lane = threadIdx.x & 63;
    const int wid = threadIdx.x >> 6;
    if (lane == 0) {
        #pragma unroll
        for (int k = 0; k < 5; ++k) red[wid][k] = vals[k];
    }
    __syncthreads();
    if (threadIdx.x == 0) {
        #pragma unroll
        for (int k = 0; k < 5; ++k)
            part[blk * 5 + k] =
                (double)(red[0][k] + red[1][k] + red[2][k] + red[3][k]);
    }
}

__global__ void dice_final(const double* __restrict__ part, float* __restrict__ out)
{
    // One wave reduces all 1024 block-partials (every slot written this call).
    double acc[BATCH][5] = {};
    for (unsigned blk = threadIdx.x; blk < (unsigned)NBLK; blk += 64) {
        const unsigned b = blk >> 9;
        #pragma unroll
        for (int k = 0; k < 5; ++k) acc[b][k] += part[blk * 5 + k];
    }
    #pragma unroll
    for (int b = 0; b < BATCH; ++b)
        #pragma unroll
        for (int k = 0; k < 5; ++k) {
            double v = acc[b][k];
            #pragma unroll
            for (int off = 32; off > 0; off >>= 1) v += __shfl_down(v, off, 64);
            acc[b][k] = v;
        }
    if (threadIdx.x == 0) {
        double total = 0.0;
        for (int b = 0; b < BATCH; ++b) {
            const double s1 = acc[b][0], q1 = acc[b][1];
            const double s2 = acc[b][2], q2 = acc[b][3];
            const double cnt = acc[b][4];
            const double den1 = q1 + cnt + (double)ORGANS * EPS;
            const double den2 = q2 + cnt + (double)ORGANS * EPS;
            total += 2.0 - (2.0 * s1 / den1 + 2.0 * s2 / den2);
        }
        *out = (float)(total / BATCH);
    }
}

extern "C" void kernel_launch(void* const* d_in, const int* in_sizes, int n_in,
                              void* d_out, int out_size, void* d_ws, size_t ws_size,
                              hipStream_t stream)
{
    const float* p1 = (const float*)d_in[0];
    const float* p2 = (const float*)d_in[1];
    const int* tg = (const int*)d_in[2];
    float* out = (float*)d_out;
    double* part = (double*)d_ws;    // 1024*5 doubles = 40 KB scratch

    dice_stream<<<dim3(NBLK), dim3(TPB), 0, stream>>>(p1, p2, tg, part);
    dice_final<<<1, 64, 0, stream>>>(part, out);
}

// Round 5
// 144.060 us; speedup vs baseline: 1.4349x; 1.0892x over previous
//
#include <hip/hip_runtime.h>

// DiceLoss: B=2, C=14, D=48, H=256, W=256, organs 1..13, weights all 1.0.
// Per batch b: S = sum of pred at target channel (t in 1..13),
//              Q = sum over c=1..13 of pred[c]^2, cnt = #{t>=1}.
// dice_stage = 2S/(Q + cnt + 13*EPS); out = mean_b(2 - dice1 - dice2).
//
// R5: register-staged loads cap in-flight bytes at the register file
// (R3/R4 both ~4.6 TB/s). This version streams pred through an 8-slot LDS
// ring via global_load_lds (width 16): 7 x 1KB tiles in flight per wave,
// counted vmcnt(6), ZERO barriers (each wave touches only its own quarter
// of each ring slot). Target window read once into 6 packed registers.

namespace {
constexpr int BATCH = 2;
constexpr int CH = 14;
constexpr int ORGANS = 13;
constexpr unsigned NV4 = 786432u;        // vec4 groups per (b, channel) slice
constexpr int TPB = 256;
constexpr int NBLK = 1024;               // 512 per batch, 4/CU exactly
constexpr unsigned WIN = 1536u;          // groups per block window (512*1536 = NV4)
constexpr int KT = 6;                    // tiles per (c, stage): WIN/256
constexpr int TILES = ORGANS * 2 * KT;   // 156
constexpr int NBUF = 8;                  // ring slots (4 KB each)
constexpr int DEPTH = 7;                 // tiles in flight per wave
constexpr double EPS = 1e-05;
}

__global__ __launch_bounds__(TPB, 4) void dice_lds(
    const float* __restrict__ p1g, const float* __restrict__ p2g,
    const int* __restrict__ tg, double* __restrict__ part)
{
    __shared__ float4 ring[NBUF][TPB];   // 32 KB ring
    __shared__ float red[4][5];

    const unsigned blk = blockIdx.x;
    const unsigned b = blk >> 9;                 // batch
    const unsigned w0 = (blk & 511u) * WIN;      // window start (groups)
    const unsigned tid = threadIdx.x;
    const unsigned wid = tid >> 6;

    // ---- Phase 0: target window once -> cnt + 6 packed label words ----
    unsigned tw[KT];
    float cn = 0.f;
    {
        const int4* __restrict__ pT =
            reinterpret_cast<const int4*>(tg) + b * NV4 + w0;
        #pragma unroll
        for (int k = 0; k < KT; ++k) {
            const int4 t = pT[k * TPB + tid];
            cn += (float)((t.x > 0) + (t.y > 0) + (t.z > 0) + (t.w > 0));
            tw[k] = (unsigned)t.x | ((unsigned)t.y << 8)
                  | ((unsigned)t.z << 16) | ((unsigned)t.w << 24);
        }
    }

    // ---- Streaming phase: 156 tiles, ring of 8, depth 7, no barriers ----
    const float* __restrict__ bases[2] = { p1g, p2g };
    const unsigned ldsq = wid * 64u;             // this wave's quarter (float4 idx)

    auto issue = [&](unsigned ti) {
        const unsigned ci = ti / (2u * KT);
        const unsigned rem = ti - ci * (2u * KT);
        const unsigned si = (rem >= (unsigned)KT) ? 1u : 0u;
        const unsigned ki = rem - si * (unsigned)KT;
        const float* src = bases[si]
            + ((unsigned long long)(b * CH + 1u + ci) * NV4 + w0 + ki * TPB + tid) * 4ull;
        const unsigned slot = ti & (NBUF - 1);
        __builtin_amdgcn_global_load_lds(
            (const __attribute__((address_space(1))) unsigned*)src,
            (__attribute__((address_space(3))) unsigned*)&ring[slot][ldsq],
            16, 0, 0);
    };

    for (unsigned ti = 0; ti < (unsigned)DEPTH; ++ti) issue(ti);

    float s1 = 0.f, q1 = 0.f, s2 = 0.f, q2 = 0.f;
    unsigned ti = 0;
    for (unsigned c = 0; c < (unsigned)ORGANS; ++c) {
        const unsigned cc = c + 1u;
        #pragma unroll
        for (int s = 0; s < 2; ++s) {
            #pragma unroll
            for (int k = 0; k < KT; ++k, ++ti) {
                if (ti + DEPTH < (unsigned)TILES) {
                    // keep 7 in flight; wait only until tile ti has landed
                    asm volatile("s_waitcnt vmcnt(6)" ::: "memory");
                    issue(ti + DEPTH);
                } else {
                    asm volatile("s_waitcnt vmcnt(0)" ::: "memory");
                }
                const float4 A = ring[ti & (NBUF - 1)][tid];
                const unsigned t4 = tw[k];
                const bool ex = ((t4 & 255u) == cc);
                const bool ey = (((t4 >> 8) & 255u) == cc);
                const bool ez = (((t4 >> 16) & 255u) == cc);
                const bool ew = ((t4 >> 24) == cc);
                if (s == 0) {
                    q1 = fmaf(A.x, A.x, q1); q1 = fmaf(A.y, A.y, q1);
                    q1 = fmaf(A.z, A.z, q1); q1 = fmaf(A.w, A.w, q1);
                    s1 += (ex ? A.x : 0.f) + (ey ? A.y : 0.f)
                        + (ez ? A.z : 0.f) + (ew ? A.w : 0.f);
                } else {
                    q2 = fmaf(A.x, A.x, q2); q2 = fmaf(A.y, A.y, q2);
                    q2 = fmaf(A.z, A.z, q2); q2 = fmaf(A.w, A.w, q2);
                    s2 += (ex ? A.x : 0.f) + (ey ? A.y : 0.f)
                        + (ez ? A.z : 0.f) + (ew ? A.w : 0.f);
                }
            }
        }
    }

    // ---- Block reduction: wave shuffle then LDS across 4 waves ----
    float vals[5] = {s1, q1, s2, q2, cn};
    #pragma unroll
    for (int k = 0; k < 5; ++k) {
        float v = vals[k];
        #pragma unroll
        for (int off = 32; off > 0; off >>= 1) v += __shfl_down(v, off, 64);
        vals[k] = v;
    }
    const int lane = tid & 63;
    if (lane == 0) {
        #pragma unroll
        for (int k = 0; k < 5; ++k) red[wid][k] = vals[k];
    }
    __syncthreads();
    if (tid == 0) {
        #pragma unroll
        for (int k = 0; k < 5; ++k)
            part[blk * 5 + k] =
                (double)(red[0][k] + red[1][k] + red[2][k] + red[3][k]);
    }
}

__global__ void dice_final(const double* __restrict__ part, float* __restrict__ out)
{
    double acc[BATCH][5] = {};
    for (unsigned blk = threadIdx.x; blk < (unsigned)NBLK; blk += 64) {
        const unsigned b = blk >> 9;
        #pragma unroll
        for (int k = 0; k < 5; ++k) acc[b][k] += part[blk * 5 + k];
    }
    #pragma unroll
    for (int b = 0; b < BATCH; ++b)
        #pragma unroll
        for (int k = 0; k < 5; ++k) {
            double v = acc[b][k];
            #pragma unroll
            for (int off = 32; off > 0; off >>= 1) v += __shfl_down(v, off, 64);
            acc[b][k] = v;
        }
    if (threadIdx.x == 0) {
        double total = 0.0;
        for (int b = 0; b < BATCH; ++b) {
            const double s1 = acc[b][0], q1 = acc[b][1];
            const double s2 = acc[b][2], q2 = acc[b][3];
            const double cnt = acc[b][4];
            const double den1 = q1 + cnt + (double)ORGANS * EPS;
            const double den2 = q2 + cnt + (double)ORGANS * EPS;
            total += 2.0 - (2.0 * s1 / den1 + 2.0 * s2 / den2);
        }
        *out = (float)(total / BATCH);
    }
}

extern "C" void kernel_launch(void* const* d_in, const int* in_sizes, int n_in,
                              void* d_out, int out_size, void* d_ws, size_t ws_size,
                              hipStream_t stream)
{
    const float* p1 = (const float*)d_in[0];
    const float* p2 = (const float*)d_in[1];
    const int* tg = (const int*)d_in[2];
    float* out = (float*)d_out;
    double* part = (double*)d_ws;    // 1024*5 doubles; every slot written per call

    dice_lds<<<dim3(NBLK), dim3(TPB), 0, stream>>>(p1, p2, tg, part);
    dice_final<<<1, 64, 0, stream>>>(part, out);
}

// Round 6
// 139.222 us; speedup vs baseline: 1.4847x; 1.0347x over previous
//
#include <hip/hip_runtime.h>

// DiceLoss: B=2, C=14, D=48, H=256, W=256, organs 1..13, weights all 1.0.
// Per batch b: S = sum of pred at target channel (t in 1..13),
//              Q = sum over c=1..13 of pred[c]^2, cnt = #{t>=1}.
// dice_stage = 2S/(Q + cnt + 13*EPS); out = mean_b(2 - dice1 - dice2).
//
// R6: R5's LDS ring (global_load_lds width-16, counted vmcnt, no barriers)
// at 2x occupancy: 16 KB ring (NBUF=4, DEPTH=3), 2048 blocks,
// __launch_bounds__(256,8) -> 8 blocks/CU = 32 waves/CU. More independent
// wave streams to fill the TA/L2 request queues (R5 ran 16 waves/CU at
// ~5.0 TB/s; harness fills prove ~6.8 TB/s is reachable).

namespace {
constexpr int BATCH = 2;
constexpr int CH = 14;
constexpr int ORGANS = 13;
constexpr unsigned NV4 = 786432u;        // vec4 groups per (b, channel) slice
constexpr int TPB = 256;
constexpr int NBLK = 2048;               // 1024 per batch, 8/CU exactly
constexpr unsigned WIN = 768u;           // groups per block window (1024*768 = NV4)
constexpr int KT = 3;                    // tiles per (c, stage): WIN/256
constexpr int TILES = ORGANS * 2 * KT;   // 78
constexpr int NBUF = 4;                  // ring slots (4 KB each) -> 16 KB
constexpr int DEPTH = 3;                 // tiles in flight per wave
constexpr double EPS = 1e-05;
}

__global__ __launch_bounds__(TPB, 8) void dice_lds(
    const float* __restrict__ p1g, const float* __restrict__ p2g,
    const int* __restrict__ tg, double* __restrict__ part)
{
    __shared__ float4 ring[NBUF][TPB];   // 16 KB ring
    __shared__ float red[4][5];

    const unsigned blk = blockIdx.x;
    const unsigned b = blk >> 10;                // batch
    const unsigned w0 = (blk & 1023u) * WIN;     // window start (groups)
    const unsigned tid = threadIdx.x;
    const unsigned wid = tid >> 6;

    // ---- Phase 0: target window once -> cnt + KT packed label words ----
    unsigned tw[KT];
    float cn = 0.f;
    {
        const int4* __restrict__ pT =
            reinterpret_cast<const int4*>(tg) + b * NV4 + w0;
        #pragma unroll
        for (int k = 0; k < KT; ++k) {
            const int4 t = pT[k * TPB + tid];
            cn += (float)((t.x > 0) + (t.y > 0) + (t.z > 0) + (t.w > 0));
            tw[k] = (unsigned)t.x | ((unsigned)t.y << 8)
                  | ((unsigned)t.z << 16) | ((unsigned)t.w << 24);
        }
    }

    // ---- Streaming phase: 78 tiles, ring of 4, depth 3, no barriers ----
    // Window base for channel 1 of each stage (float4 index space).
    const float4* __restrict__ pS0 =
        reinterpret_cast<const float4*>(p1g) + (unsigned long long)(b * CH + 1) * NV4 + w0;
    const float4* __restrict__ pS1 =
        reinterpret_cast<const float4*>(p2g) + (unsigned long long)(b * CH + 1) * NV4 + w0;
    const unsigned ldsq = wid * 64u;             // this wave's quarter (float4 idx)

    auto issue = [&](unsigned ti) {
        const unsigned ci = ti / (2u * KT);
        const unsigned rem = ti - ci * (2u * KT);
        const unsigned si = (rem >= (unsigned)KT) ? 1u : 0u;
        const unsigned ki = rem - si * (unsigned)KT;
        const float4* src = (si ? pS1 : pS0) + (ci * NV4 + ki * TPB + tid);
        const unsigned slot = ti & (NBUF - 1);
        __builtin_amdgcn_global_load_lds(
            (const __attribute__((address_space(1))) unsigned*)src,
            (__attribute__((address_space(3))) unsigned*)&ring[slot][ldsq],
            16, 0, 0);
    };

    for (unsigned ti = 0; ti < (unsigned)DEPTH; ++ti) issue(ti);

    float s1 = 0.f, q1 = 0.f, s2 = 0.f, q2 = 0.f;
    unsigned ti = 0;
    for (unsigned c = 0; c < (unsigned)ORGANS; ++c) {
        const unsigned cc = c + 1u;
        #pragma unroll
        for (int s = 0; s < 2; ++s) {
            #pragma unroll
            for (int k = 0; k < KT; ++k, ++ti) {
                if (ti + DEPTH < (unsigned)TILES) {
                    // keep DEPTH in flight; wait only until tile ti landed
                    asm volatile("s_waitcnt vmcnt(2)" ::: "memory");
                    issue(ti + DEPTH);
                } else {
                    asm volatile("s_waitcnt vmcnt(0)" ::: "memory");
                }
                const float4 A = ring[ti & (NBUF - 1)][tid];
                const unsigned t4 = tw[k];
                const bool ex = ((t4 & 255u) == cc);
                const bool ey = (((t4 >> 8) & 255u) == cc);
                const bool ez = (((t4 >> 16) & 255u) == cc);
                const bool ew = ((t4 >> 24) == cc);
                if (s == 0) {
                    q1 = fmaf(A.x, A.x, q1); q1 = fmaf(A.y, A.y, q1);
                    q1 = fmaf(A.z, A.z, q1); q1 = fmaf(A.w, A.w, q1);
                    s1 += (ex ? A.x : 0.f) + (ey ? A.y : 0.f)
                        + (ez ? A.z : 0.f) + (ew ? A.w : 0.f);
                } else {
                    q2 = fmaf(A.x, A.x, q2); q2 = fmaf(A.y, A.y, q2);
                    q2 = fmaf(A.z, A.z, q2); q2 = fmaf(A.w, A.w, q2);
                    s2 += (ex ? A.x : 0.f) + (ey ? A.y : 0.f)
                        + (ez ? A.z : 0.f) + (ew ? A.w : 0.f);
                }
            }
        }
    }

    // ---- Block reduction: wave shuffle then LDS across 4 waves ----
    float vals[5] = {s1, q1, s2, q2, cn};
    #pragma unroll
    for (int k = 0; k < 5; ++k) {
        float v = vals[k];
        #pragma unroll
        for (int off = 32; off > 0; off >>= 1) v += __shfl_down(v, off, 64);
        vals[k] = v;
    }
    const int lane = tid & 63;
    if (lane == 0) {
        #pragma unroll
        for (int k = 0; k < 5; ++k) red[wid][k] = vals[k];
    }
    __syncthreads();
    if (tid == 0) {
        #pragma unroll
        for (int k = 0; k < 5; ++k)
            part[blk * 5 + k] =
                (double)(red[0][k] + red[1][k] + red[2][k] + red[3][k]);
    }
}

__global__ __launch_bounds__(256) void dice_final(
    const double* __restrict__ part, float* __restrict__ out)
{
    __shared__ double redd[BATCH][4][5];
    const int tid = threadIdx.x, lane = tid & 63, wv = tid >> 6;
    #pragma unroll
    for (int b = 0; b < BATCH; ++b) {
        double loc[5] = {0, 0, 0, 0, 0};
        for (int i = tid; i < NBLK / BATCH; i += 256) {
            const double* p = part + ((unsigned)(b * (NBLK / BATCH) + i)) * 5u;
            #pragma unroll
            for (int k = 0; k < 5; ++k) loc[k] += p[k];
        }
        #pragma unroll
        for (int k = 0; k < 5; ++k) {
            double v = loc[k];
            #pragma unroll
            for (int off = 32; off > 0; off >>= 1) v += __shfl_down(v, off, 64);
            loc[k] = v;
        }
        if (lane == 0) {
            #pragma unroll
            for (int k = 0; k < 5; ++k) redd[b][wv][k] = loc[k];
        }
    }
    __syncthreads();
    if (tid == 0) {
        double total = 0.0;
        #pragma unroll
        for (int b = 0; b < BATCH; ++b) {
            double a[5];
            #pragma unroll
            for (int k = 0; k < 5; ++k)
                a[k] = redd[b][0][k] + redd[b][1][k] + redd[b][2][k] + redd[b][3][k];
            const double den1 = a[1] + a[4] + (double)ORGANS * EPS;
            const double den2 = a[3] + a[4] + (double)ORGANS * EPS;
            total += 2.0 - (2.0 * a[0] / den1 + 2.0 * a[2] / den2);
        }
        *out = (float)(total / BATCH);
    }
}

extern "C" void kernel_launch(void* const* d_in, const int* in_sizes, int n_in,
                              void* d_out, int out_size, void* d_ws, size_t ws_size,
                              hipStream_t stream)
{
    const float* p1 = (const float*)d_in[0];
    const float* p2 = (const float*)d_in[1];
    const int* tg = (const int*)d_in[2];
    float* out = (float*)d_out;
    double* part = (double*)d_ws;    // 2048*5 doubles = 80 KB; all written per call

    dice_lds<<<dim3(NBLK), dim3(TPB), 0, stream>>>(p1, p2, tg, part);
    dice_final<<<1, 256, 0, stream>>>(part, out);
}